// Round 13
// baseline (98.305 us; speedup 1.0000x reference)
//
#include <hip/hip_runtime.h>
#include <math.h>

#define B 8
#define C 512
#define L 8192
#define N 512      // L/CS chunk steps
#define C8 64      // C/8 bottleneck dim
#define CTILE 8    // channels per pool_ema block
#define NT2 4      // chunk rows per se_apply block
#define GSTRIDE 516  // gate LDS row stride (conflict-free apply reads)
#define BH 4       // batches per phase (L3 capacity: 2*16.8*BH + e < 256 MB)

// ---------------------------------------------------------------------------
// Kernel 1: fused pooling + full causal EMA.  x [B,C,L] -> e [B,N,C]
// Block = (b, 8-channel tile); owns the whole N timeline for its channels.
// Phase-split: handles batches [b0, b0+BH).
// ---------------------------------------------------------------------------
__global__ __launch_bounds__(256) void pool_ema_k(
    const float* __restrict__ x, const float* __restrict__ gamma,
    float* __restrict__ e,
    const float* __restrict__ w1, const float* __restrict__ w2,
    float* __restrict__ w1t4, float* __restrict__ w2t4, int b0) {
    // per-channel stride 545 dwords: addr = cl*545 + s*17 + i  (s=seg, i=step)
    __shared__ float cm[CTILE * 545];
    __shared__ float carry_s[CTILE][32];
    __shared__ float pre_s[CTILE][32];
    const int t = threadIdx.x;
    const int bid = blockIdx.x;          // BH * 64 = 256
    const int ct = bid & 63;
    const int b = b0 + (bid >> 6);

    // weight repack (first 128 blocks' threads; only in the b0==0 launch)
    const int gid = bid * 256 + t;
    if (b0 == 0 && gid < C8 * C) {
        const int o = gid >> 9, k = gid & (C - 1);
        w1t4[((k >> 2) * C8 + o) * 4 + (k & 3)] = w1[gid];
        const int c2 = gid >> 6, k2 = gid & (C8 - 1);
        w2t4[((k2 >> 2) * C + c2) * 4 + (k2 & 3)] = w2[gid];
    }

    const int w = t >> 6, lane = t & 63;
    // ---- Phase A: chunk means (coalesced float4 reads, 8-deep) ----
#pragma unroll
    for (int cr = 0; cr < 2; ++cr) {
        const int cl = w + 4 * cr;
        const size_t row4 = (size_t)(b * C + ct * CTILE + cl) * (L / 4);
#pragma unroll
        for (int rr = 0; rr < 4; ++rr) {
            float4 f[8];
#pragma unroll
            for (int u = 0; u < 8; ++u)
                f[u] = reinterpret_cast<const float4*>(x)[row4 + rr * 512 + u * 64 + lane];
#pragma unroll
            for (int u = 0; u < 8; ++u) {
                float s = f[u].x + f[u].y + f[u].z + f[u].w;
                s += __shfl_down(s, 1, 4);
                s += __shfl_down(s, 2, 4);
                if ((lane & 3) == 0) {
                    const int chunk = rr * 128 + u * 16 + (lane >> 2);
                    cm[cl * 545 + (chunk >> 4) * 17 + (chunk & 15)] = s * (1.0f / 16.0f);
                }
            }
        }
    }
    __syncthreads();

    // ---- Phase B: EMA segmented scan (32 seg x 16 steps) ----
    const int cl = t >> 5, s = t & 31;
    const float g = gamma[ct * CTILE + cl];
    const float omg = 1.0f - g;
    {
        float y = 0.0f;
#pragma unroll
        for (int i = 0; i < 16; ++i)
            y = fmaf(g, y, omg * cm[cl * 545 + s * 17 + i]);
        carry_s[cl][s] = y;
    }
    __syncthreads();
    if (t < CTILE) {
        const float gg = gamma[ct * CTILE + t];
        float g16 = gg * gg; g16 *= g16; g16 *= g16; g16 *= g16;   // g^16
        float E = 0.0f;
#pragma unroll
        for (int ss = 0; ss < 32; ++ss) {
            pre_s[t][ss] = E;
            E = fmaf(g16, E, carry_s[t][ss]);
        }
    }
    __syncthreads();
    {
        float y = pre_s[cl][s];
#pragma unroll
        for (int i = 0; i < 16; ++i) {
            y = fmaf(g, y, omg * cm[cl * 545 + s * 17 + i]);
            cm[cl * 545 + s * 17 + i] = y;
        }
    }
    __syncthreads();

    // ---- write e [B,N,C] ----
    float* ebase = e + (size_t)b * N * C + ct * CTILE;
#pragma unroll
    for (int rr = 0; rr < 16; ++rr) {
        const int idx = rr * 256 + t;
        const int n = idx >> 3, c2 = idx & 7;
        ebase[(size_t)n * C + c2] = cm[c2 * 545 + (n >> 4) * 17 + (n & 15)];
    }
}

// ---------------------------------------------------------------------------
// Kernel 2: fused SE + apply for batches [b0, b0+BH).
// Block = (b, 4 chunk-rows). e[4][512] -> GEMM1 -> GEMM2 -> gate in LDS ->
// apply to x slice. x re-read is L3-guaranteed: phase working set
// (x-half 67 + out-half 67 + e 4 MB) < 256 MB Infinity Cache.
// ---------------------------------------------------------------------------
__global__ __launch_bounds__(256) void se_apply_k(
    const float* __restrict__ e, const float* __restrict__ w1t4,
    const float* __restrict__ b1, const float* __restrict__ w2t4,
    const float* __restrict__ b2, const float* __restrict__ x,
    float* __restrict__ out, int b0) {
    __shared__ float es[NT2 * C];          // 8 KB
    __shared__ float hs[NT2 * C8];         // 1 KB
    __shared__ float gs[NT2 * GSTRIDE];    // 8.25 KB
    const int t = threadIdx.x;
    const int bid = blockIdx.x;            // BH * 128 = 512
    const int b = b0 + (bid >> 7);
    const int nt = bid & 127;
    const int n0 = nt * NT2;

    // stage e rows n0..n0+3 (coalesced)
    {
        const float4* esrc = reinterpret_cast<const float4*>(e + ((size_t)b * N + n0) * C);
        float4* esw = reinterpret_cast<float4*>(es);
        esw[t] = esrc[t];
        esw[256 + t] = esrc[256 + t];
    }
    __syncthreads();

    // GEMM1: h[4][64] = relu(e x w1^T + b1).  thread = (o = t&63, j = t>>6)
    {
        const int o = t & 63, j = t >> 6;
        float acc = 0.f;
        const float4* w1v = reinterpret_cast<const float4*>(w1t4);
        const float4* es4 = reinterpret_cast<const float4*>(es);
#pragma unroll 8
        for (int k4 = 0; k4 < 128; ++k4) {
            const float4 wv = w1v[k4 * C8 + o];      // consecutive o -> coalesced
            const float4 ev = es4[j * 128 + k4];     // wave-uniform -> broadcast
            acc = fmaf(wv.x, ev.x, acc); acc = fmaf(wv.y, ev.y, acc);
            acc = fmaf(wv.z, ev.z, acc); acc = fmaf(wv.w, ev.w, acc);
        }
        hs[j * C8 + o] = fmaxf(acc + b1[o], 0.f);
    }
    __syncthreads();

    // GEMM2 + sigmoid -> gs[4][512] (LDS only). thread owns c = t, t+256.
    {
        float acc0[NT2], acc1[NT2];
        const float bb0 = b2[t], bb1 = b2[t + 256];
#pragma unroll
        for (int j = 0; j < NT2; ++j) { acc0[j] = bb0; acc1[j] = bb1; }
        const float4* w2v = reinterpret_cast<const float4*>(w2t4);
        const float4* hs4 = reinterpret_cast<const float4*>(hs);
#pragma unroll
        for (int k4 = 0; k4 < 16; ++k4) {
            const float4 wa = w2v[k4 * C + t];
            const float4 wb = w2v[k4 * C + t + 256];
#pragma unroll
            for (int j = 0; j < NT2; ++j) {
                const float4 hv = hs4[j * 16 + k4];
                acc0[j] = fmaf(wa.x, hv.x, acc0[j]); acc0[j] = fmaf(wa.y, hv.y, acc0[j]);
                acc0[j] = fmaf(wa.z, hv.z, acc0[j]); acc0[j] = fmaf(wa.w, hv.w, acc0[j]);
                acc1[j] = fmaf(wb.x, hv.x, acc1[j]); acc1[j] = fmaf(wb.y, hv.y, acc1[j]);
                acc1[j] = fmaf(wb.z, hv.z, acc1[j]); acc1[j] = fmaf(wb.w, hv.w, acc1[j]);
            }
        }
#pragma unroll
        for (int j = 0; j < NT2; ++j) {
            gs[j * GSTRIDE + t]       = 1.0f / (1.0f + __expf(-acc0[j]));
            gs[j * GSTRIDE + t + 256] = 1.0f / (1.0f + __expf(-acc1[j]));
        }
    }
    __syncthreads();

    // apply: all 512 c-rows, l-range [nt*64, nt*64+64).
    {
        const size_t base4 = (size_t)b * C * (L / 4) + nt * 16;
        const float4* x4 = reinterpret_cast<const float4*>(x);
        float4* o4 = reinterpret_cast<float4*>(out);
#pragma unroll 4
        for (int i = 0; i < 32; ++i) {
            const int p = i * 256 + t;
            const int r = p >> 4;          // c row 0..511
            const int q = p & 15;          // float4 within the 64-float segment
            const float g = gs[(q >> 2) * GSTRIDE + r];
            const size_t idx = base4 + (size_t)r * (L / 4) + q;
            float4 v = x4[idx];
            v.x *= g; v.y *= g; v.z *= g; v.w *= g;
            o4[idx] = v;
        }
    }
}

// ---------------------------------------------------------------------------
extern "C" void kernel_launch(void* const* d_in, const int* in_sizes, int n_in,
                              void* d_out, int out_size, void* d_ws, size_t ws_size,
                              hipStream_t stream) {
    const float* x     = (const float*)d_in[0];
    const float* gamma = (const float*)d_in[1];
    const float* w1    = (const float*)d_in[2];
    const float* b1    = (const float*)d_in[3];
    const float* w2    = (const float*)d_in[4];
    const float* b2    = (const float*)d_in[5];
    float* out = (float*)d_out;

    char* ws = (char*)d_ws;
    size_t off = 0;
    float* e    = (float*)(ws + off); off += (size_t)B * N * C * 4;   // 8 MB
    float* w1t4 = (float*)(ws + off); off += (size_t)C8 * C * 4;      // 128 KB
    float* w2t4 = (float*)(ws + off); off += (size_t)C8 * C * 4;      // 128 KB

    // phase 0: batches 0..3   (weight repack in the first K1)
    pool_ema_k<<<BH * 64, 256, 0, stream>>>(x, gamma, e, w1, w2, w1t4, w2t4, 0);
    se_apply_k<<<BH * 128, 256, 0, stream>>>(e, w1t4, b1, w2t4, b2, x, out, 0);
    // phase 1: batches 4..7
    pool_ema_k<<<BH * 64, 256, 0, stream>>>(x, gamma, e, w1, w2, w1t4, w2t4, BH);
    se_apply_k<<<BH * 128, 256, 0, stream>>>(e, w1t4, b1, w2t4, b2, x, out, BH);
}